// Round 2
// baseline (2723.076 us; speedup 1.0000x reference)
//
#include <hip/hip_runtime.h>

#define BSZ  2048
#define TLEN 512
#define HDIM 64
#define NG   256   // 4*H gate rows
#define NB   4     // batch rows per block
#define NTH  512   // threads per block: 2 K-halves x 256 gate rows

__device__ __forceinline__ float sigm(float x) {
    return __fdividef(1.0f, 1.0f + __expf(-x));
}
__device__ __forceinline__ float tanh_(float x) {
    // tanh(x) = 1 - 2/(exp(2x)+1); stable at +/-inf
    return 1.0f - __fdividef(2.0f, __expf(2.0f * x) + 1.0f);
}

__global__ __launch_bounds__(NTH, 4)   // 4 waves/SIMD -> VGPR cap 128; demand ~125
void lstm2_fused(const float* __restrict__ x,
                 const float* __restrict__ w_ih0,
                 const float* __restrict__ w_hh0,
                 const float* __restrict__ b_ih0,
                 const float* __restrict__ b_hh0,
                 const float* __restrict__ w_ih1,
                 const float* __restrict__ w_hh1,
                 const float* __restrict__ b_ih1,
                 const float* __restrict__ b_hh1,
                 const float* __restrict__ fc_w,
                 const float* __restrict__ fc_b,
                 float* __restrict__ out)
{
    __shared__ float xs[NB][TLEN];      // 8 KB staged input rows
    __shared__ float gs[2][NB][NG];     // 8 KB gate partial sums (per K-half)
    __shared__ float h1s[NB][HDIM];     // 1 KB layer-0 hidden
    __shared__ float h2s[NB][HDIM];     // 1 KB layer-1 hidden

    const int tid  = threadIdx.x;
    const int half = tid >> 8;          // K-half 0/1 (wave-uniform)
    const int j    = tid & 255;         // gate row
    const int hb   = half * 32;         // k-slice base
    const int b0   = blockIdx.x * NB;

    // ---- stage x rows (coalesced) ----
    for (int i = tid; i < NB * TLEN; i += NTH) {
        const int bb = i >> 9;
        const int tt = i & (TLEN - 1);
        xs[bb][tt] = x[(b0 + bb) * TLEN + tt];
    }
    if (tid < NB * HDIM) {
        h1s[tid >> 6][tid & 63] = 0.0f;
        h2s[tid >> 6][tid & 63] = 0.0f;
    }

    // ---- weights register-stationary: thread owns 32-wide slice of 3 rows ----
    float w0[32], w1[32], w2[32];
    #pragma unroll
    for (int k = 0; k < 32; k += 4) {
        *(float4*)&w0[k] = *(const float4*)(w_hh0 + j * HDIM + hb + k);
        *(float4*)&w1[k] = *(const float4*)(w_ih1 + j * HDIM + hb + k);
        *(float4*)&w2[k] = *(const float4*)(w_hh1 + j * HDIM + hb + k);
    }
    const float wih0j = w_ih0[j];
    const float bias0 = (half == 0) ? (b_ih0[j] + b_hh0[j]) : 0.0f;
    const float bias1 = (half == 0) ? (b_ih1[j] + b_hh1[j]) : 0.0f;

    const int ub = (tid >> 6) & (NB - 1);  // update phase: batch row (tid<256)
    const int uk = tid & 63;               // update phase: hidden unit
    float c1 = 0.0f, c2 = 0.0f;

    __syncthreads();

    for (int t = 0; t < TLEN; ++t) {
        float a[NB];

        // ======== layer 0 gate partials: a[b] = [bias0 + x*w_ih0] + w0 . h1[hb..hb+31] ========
        if (half == 0) {
            #pragma unroll
            for (int b = 0; b < NB; ++b) a[b] = fmaf(xs[b][t], wih0j, bias0);
        } else {
            #pragma unroll
            for (int b = 0; b < NB; ++b) a[b] = 0.0f;
        }
        #pragma unroll
        for (int k = 0; k < 32; k += 4) {
            #pragma unroll
            for (int b = 0; b < NB; ++b) {
                const float4 hv = *(const float4*)&h1s[b][hb + k];
                a[b] = fmaf(w0[k    ], hv.x, a[b]);
                a[b] = fmaf(w0[k + 1], hv.y, a[b]);
                a[b] = fmaf(w0[k + 2], hv.z, a[b]);
                a[b] = fmaf(w0[k + 3], hv.w, a[b]);
            }
        }
        #pragma unroll
        for (int b = 0; b < NB; ++b) gs[half][b][j] = a[b];
        __syncthreads();

        // ======== layer 0 state update (threads 0..255 own (ub,uk)) ========
        if (tid < NB * HDIM) {
            const float gi = sigm (gs[0][ub][      uk] + gs[1][ub][      uk]);
            const float gf = sigm (gs[0][ub][ 64 + uk] + gs[1][ub][ 64 + uk]);
            const float gg = tanh_(gs[0][ub][128 + uk] + gs[1][ub][128 + uk]);
            const float go = sigm (gs[0][ub][192 + uk] + gs[1][ub][192 + uk]);
            c1 = fmaf(gf, c1, gi * gg);
            h1s[ub][uk] = go * tanh_(c1);
        }
        __syncthreads();

        // ======== layer 1 gate partials: a[b] = bias1 + w1 . h1_new[slice] + w2 . h2[slice] ========
        #pragma unroll
        for (int b = 0; b < NB; ++b) a[b] = bias1;   // bias1 is 0 for half==1
        #pragma unroll
        for (int k = 0; k < 32; k += 4) {
            #pragma unroll
            for (int b = 0; b < NB; ++b) {
                const float4 h1v = *(const float4*)&h1s[b][hb + k];
                a[b] = fmaf(w1[k    ], h1v.x, a[b]);
                a[b] = fmaf(w1[k + 1], h1v.y, a[b]);
                a[b] = fmaf(w1[k + 2], h1v.z, a[b]);
                a[b] = fmaf(w1[k + 3], h1v.w, a[b]);
                const float4 h2v = *(const float4*)&h2s[b][hb + k];
                a[b] = fmaf(w2[k    ], h2v.x, a[b]);
                a[b] = fmaf(w2[k + 1], h2v.y, a[b]);
                a[b] = fmaf(w2[k + 2], h2v.z, a[b]);
                a[b] = fmaf(w2[k + 3], h2v.w, a[b]);
            }
        }
        #pragma unroll
        for (int b = 0; b < NB; ++b) gs[half][b][j] = a[b];
        __syncthreads();

        // ======== layer 1 state update ========
        if (tid < NB * HDIM) {
            const float gi = sigm (gs[0][ub][      uk] + gs[1][ub][      uk]);
            const float gf = sigm (gs[0][ub][ 64 + uk] + gs[1][ub][ 64 + uk]);
            const float gg = tanh_(gs[0][ub][128 + uk] + gs[1][ub][128 + uk]);
            const float go = sigm (gs[0][ub][192 + uk] + gs[1][ub][192 + uk]);
            c2 = fmaf(gf, c2, gi * gg);
            h2s[ub][uk] = go * tanh_(c2);
        }
        __syncthreads();
    }

    // ======== final FC on last h2 ========
    if (tid < NB) {
        float s = fc_b[0];
        #pragma unroll
        for (int k = 0; k < HDIM; ++k)
            s = fmaf(fc_w[k], h2s[tid][k], s);
        out[b0 + tid] = s;
    }
}

extern "C" void kernel_launch(void* const* d_in, const int* in_sizes, int n_in,
                              void* d_out, int out_size, void* d_ws, size_t ws_size,
                              hipStream_t stream) {
    const float* xp     = (const float*)d_in[0];
    const float* w_ih0  = (const float*)d_in[1];
    const float* w_hh0  = (const float*)d_in[2];
    const float* b_ih0  = (const float*)d_in[3];
    const float* b_hh0  = (const float*)d_in[4];
    const float* w_ih1  = (const float*)d_in[5];
    const float* w_hh1  = (const float*)d_in[6];
    const float* b_ih1  = (const float*)d_in[7];
    const float* b_hh1  = (const float*)d_in[8];
    const float* fc_w   = (const float*)d_in[9];
    const float* fc_b   = (const float*)d_in[10];
    float* outp = (float*)d_out;

    dim3 grid(BSZ / NB);   // 512 blocks x 512 threads = 2 blocks/CU
    dim3 block(NTH);
    lstm2_fused<<<grid, block, 0, stream>>>(xp, w_ih0, w_hh0, b_ih0, b_hh0,
                                            w_ih1, w_hh1, b_ih1, b_hh1,
                                            fc_w, fc_b, outp);
}